// Round 6
// baseline (175.956 us; speedup 1.0000x reference)
//
#include <hip/hip_runtime.h>
#include <hip/hip_bf16.h>
#include <cstdint>
#include <cstddef>

#define B_N   32
#define CIN_  128
#define COUT_ 128
#define KW_   7
#define L_    4096
#define NW_   256      // w-positions per block tile
#define NWELEM (KW_ * COUT_ * CIN_)   // 114688

#define SX_ROWS  264                  // 262 used (256 w + 6 taps); pad to 264
#define SX_ELEMS (SX_ROWS * CIN_)     // 33792 bf16 = 67584 B

typedef __attribute__((ext_vector_type(8))) short  bf16x8;
typedef __attribute__((ext_vector_type(4))) float  f32x4;

// Weight prep: ewb written directly in MFMA fragment order.
// idx = (((t*8+og)*4+cc)*64 + li)*8 + e  holds
// exp(W[og*16+(li&15)][cc*32+(li>>4)*8+e]) at tap t, so tropconv loads a
// whole A-fragment as one coalesced 1KB wave read straight into VGPRs.
__global__ __launch_bounds__(256) void prep_w_kernel(
        const float* __restrict__ w, __hip_bfloat16* __restrict__ ewb) {
    int base = blockIdx.x * 1024 + threadIdx.x;
    #pragma unroll
    for (int i = 0; i < 4; ++i) {
        int idx = base + 256 * i;                   // 112 blocks cover 114688
        int e  = idx & 7;
        int li = (idx >> 3) & 63;
        int cc = (idx >> 9) & 3;
        int blk = idx >> 11;                        // 0..55
        int og = blk & 7, t = blk >> 3;
        int o  = og * 16 + (li & 15);
        int ch = cc * 32 + ((li >> 4) << 3) + e;
        ewb[idx] = __float2bfloat16(__expf(w[(o * CIN_ + ch) * KW_ + t]));
    }
}

// Fused conv GEMM (Round 6): exp_x kernel and the exT intermediate are GONE.
// Each block stages x[b, :, w0-3..w0+258] (134 KB f32) directly from global,
// applying exp + bf16-cvt + transpose on the fly into swizzled sX.
//  - reads coalesced: wave = 4 rows x 256 B (f32x4/lane)
//  - LDS scatter: 2B writes, row-stride 256 B; swizzle perm(p)=(p^(p>>2))&7
//    gives 8-distinct slots across the lanes' p-values -> <=4-way writes;
//    read side keeps the twice-per-quad multiset that measured 0 conflicts.
//  - edge blocks (w0=0,3840): address clamp + per-element zero select gives
//    exp-space zero padding; p-window predicate drops out-of-tile elements.
// Compute core and epilogue identical to R5 (A global->VGPR from fragment-
// ordered ewb, B-only LDS at 0.25 KB-reads/MFMA, one barrier per block,
// 2 de-phased blocks/CU for TLP overlap of stage/compute/epilogue).
__global__ __launch_bounds__(256, 2) void tropconv_kernel(
        const float* __restrict__ x,
        const __hip_bfloat16* __restrict__ ewb,
        const float* __restrict__ bias,
        float* __restrict__ out) {
    __shared__ __align__(16) __hip_bfloat16 sX[SX_ELEMS];   // 67584 B

    const int tid  = threadIdx.x;
    const int lane = tid & 63;
    const int wave = tid >> 6;
    const int wm   = wave >> 1;            // 0..1: o half (64 each)
    const int wn   = wave & 1;             // 0..1: w half (128 each)
    const int l15  = lane & 15;
    const int q    = lane >> 4;

    const int b  = blockIdx.y;
    const int w0 = blockIdx.x * NW_;
    const float* xb = x + (size_t)b * CIN_ * L_;

    // ---- fused stage: 128 rows x 66 granules (16B f32x4), granule g covers
    // l = w0-4+4g .. +3, written to rows p = l-w0+3 in [0,262).
    #pragma unroll
    for (int i = 0; i < 8; ++i) {
        int idx = tid + 256 * i;
        int c   = idx >> 4;                // 0..127
        int gb  = idx & 15;
        int cHi = c >> 3, cLo = c & 7;
        #pragma unroll
        for (int j = 0; j < 5; ++j) {
            int g = gb + 16 * j;
            if (g >= 66) continue;         // j==4 partial (gb<2)
            int l0  = w0 - 4 + 4 * g;
            int l0c = min(max(l0, 0), L_ - 4);      // clamp keeps loads in-buffer;
            f32x4 v = *(const f32x4*)(xb + (size_t)c * L_ + l0c);
            #pragma unroll
            for (int e = 0; e < 4; ++e) {
                int l = l0 + e;
                int p = 4 * g + e - 1;              // = l - w0 + 3
                if ((unsigned)p < 262u) {
                    // clamped granules have ALL elems out-of-range (l0 mult of 4)
                    float val = ((unsigned)l < (unsigned)L_) ? __expf(v[e]) : 0.0f;
                    int slot = cHi ^ ((p ^ (p >> 2)) & 7);
                    sX[(p << 7) + (slot << 3) + cLo] = __float2bfloat16(val);
                }
            }
        }
    }

    f32x4 acc[4][8];
    #pragma unroll
    for (int i = 0; i < 4; ++i)
        #pragma unroll
        for (int j = 0; j < 8; ++j)
            acc[i][j] = (f32x4){0.f, 0.f, 0.f, 0.f};

    __syncthreads();                       // the block's ONE barrier

    // A-frag (t,cc,mi): 1KB coalesced global load, lane li holds
    // W[og*16+(li&15)][cc*32+(li>>4)*8..+8], og = wm*4+mi.
#define ALOAD(AF, T, CC)                                                     \
    do {                                                                     \
        _Pragma("unroll")                                                    \
        for (int mi = 0; mi < 4; ++mi)                                       \
            AF[mi] = *(const bf16x8*)&ewb[(((((T) * 8 + wm * 4 + mi) * 4     \
                                             + (CC)) << 6) + lane) * 8];     \
    } while (0)

    // B-reads + 32 MFMAs for one (tap, chunk); b128 per lane, ~2/quad banks.
#define BDOT(AF, T, CC)                                                      \
    do {                                                                     \
        bf16x8 bx[8];                                                        \
        _Pragma("unroll")                                                    \
        for (int ni = 0; ni < 8; ++ni) {                                     \
            int p = wn * 128 + ni * 16 + l15 + (T);                          \
            int g = ((CC) * 4 + q) ^ ((p ^ (p >> 2)) & 7);                   \
            bx[ni] = *(const bf16x8*)&sX[(p << 7) + (g << 3)];               \
        }                                                                    \
        __builtin_amdgcn_s_setprio(1);                                       \
        _Pragma("unroll")                                                    \
        for (int mi = 0; mi < 4; ++mi)                                       \
            _Pragma("unroll")                                                \
            for (int ni = 0; ni < 8; ++ni)                                   \
                acc[mi][ni] = __builtin_amdgcn_mfma_f32_16x16x32_bf16(       \
                    AF[mi], bx[ni], acc[mi][ni], 0, 0, 0);                   \
        __builtin_amdgcn_s_setprio(0);                                       \
    } while (0)

    {
        bf16x8 afA[4], afB[4];
        ALOAD(afA, 0, 0);
        ALOAD(afB, 1, 0);  BDOT(afA, 0, 0);
        ALOAD(afA, 2, 0);  BDOT(afB, 1, 0);
        ALOAD(afB, 3, 0);  BDOT(afA, 2, 0);
        ALOAD(afA, 4, 0);  BDOT(afB, 3, 0);
        ALOAD(afB, 5, 0);  BDOT(afA, 4, 0);
        ALOAD(afA, 6, 0);  BDOT(afB, 5, 0);
        ALOAD(afB, 0, 1);  BDOT(afA, 6, 0);
        ALOAD(afA, 1, 1);  BDOT(afB, 0, 1);
        ALOAD(afB, 2, 1);  BDOT(afA, 1, 1);
        ALOAD(afA, 3, 1);  BDOT(afB, 2, 1);
        ALOAD(afB, 4, 1);  BDOT(afA, 3, 1);
        ALOAD(afA, 5, 1);  BDOT(afB, 4, 1);
        ALOAD(afB, 6, 1);  BDOT(afA, 5, 1);
        ALOAD(afA, 0, 2);  BDOT(afB, 6, 1);
        ALOAD(afB, 1, 2);  BDOT(afA, 0, 2);
        ALOAD(afA, 2, 2);  BDOT(afB, 1, 2);
        ALOAD(afB, 3, 2);  BDOT(afA, 2, 2);
        ALOAD(afA, 4, 2);  BDOT(afB, 3, 2);
        ALOAD(afB, 5, 2);  BDOT(afA, 4, 2);
        ALOAD(afA, 6, 2);  BDOT(afB, 5, 2);
        ALOAD(afB, 0, 3);  BDOT(afA, 6, 2);
        ALOAD(afA, 1, 3);  BDOT(afB, 0, 3);
        ALOAD(afB, 2, 3);  BDOT(afA, 1, 3);
        ALOAD(afA, 3, 3);  BDOT(afB, 2, 3);
        ALOAD(afB, 4, 3);  BDOT(afA, 3, 3);
        ALOAD(afA, 5, 3);  BDOT(afB, 4, 3);
        ALOAD(afB, 6, 3);  BDOT(afA, 5, 3);
                           BDOT(afB, 6, 3);
    }
#undef ALOAD
#undef BDOT

    // epilogue: y = log(s) + bias[o]; C/D: col=lane&15 (w), row=q*4+reg (cout)
    float* outb = out + (size_t)b * COUT_ * L_;
    #pragma unroll
    for (int mi = 0; mi < 4; ++mi) {
        #pragma unroll
        for (int r = 0; r < 4; ++r) {
            int o = wm * 64 + mi * 16 + q * 4 + r;
            float bv = bias[o];
            #pragma unroll
            for (int ni = 0; ni < 8; ++ni) {
                int w = w0 + wn * 128 + ni * 16 + l15;
                outb[(size_t)o * L_ + w] = __logf(acc[mi][ni][r]) + bv;
            }
        }
    }
}

extern "C" void kernel_launch(void* const* d_in, const int* in_sizes, int n_in,
                              void* d_out, int out_size, void* d_ws, size_t ws_size,
                              hipStream_t stream) {
    const float* x    = (const float*)d_in[0];   // (32,128,4096) f32
    const float* wgt  = (const float*)d_in[1];   // (128,128,7)   f32
    const float* bias = (const float*)d_in[2];   // (128,)        f32
    float* out = (float*)d_out;                  // (32,128,4096) f32

    // workspace: ewb only (229 KB) -- exT intermediate eliminated
    __hip_bfloat16* ewb = (__hip_bfloat16*)d_ws;

    prep_w_kernel<<<NWELEM / 1024, 256, 0, stream>>>(wgt, ewb);
    tropconv_kernel<<<dim3(L_ / NW_, B_N), 256, 0, stream>>>(x, ewb, bias, out);
}

// Round 7
// 171.711 us; speedup vs baseline: 1.0247x; 1.0247x over previous
//
#include <hip/hip_runtime.h>
#include <hip/hip_bf16.h>
#include <cstdint>
#include <cstddef>

#define B_N   32
#define CIN_  128
#define COUT_ 128
#define KW_   7
#define L_    4096
#define PAD_  3
#define NW_   128      // w-positions per block tile (R7: halved for 4 blocks/CU)
#define RPB   4104     // exT rows per batch: r = l + 3, guards r<3 and r>4098
#define NWELEM (KW_ * COUT_ * CIN_)   // 114688
#define NGUARD (B_N * 8 * CIN_)       // 32768

#define SX_ROWS  136                  // 134 used (128 w + 6 taps); pad to 136
#define SX_ELEMS (SX_ROWS * CIN_)     // 17408 bf16 = 34816 B -> 4 blocks/CU

typedef __attribute__((ext_vector_type(8))) short  bf16x8;
typedef __attribute__((ext_vector_type(4))) float  f32x4;

__device__ __forceinline__ void gl2lds16(const void* g, void* l) {
    __builtin_amdgcn_global_load_lds(
        (const __attribute__((address_space(1))) unsigned int*)g,
        (__attribute__((address_space(3))) unsigned int*)l, 16, 0, 0);
}

// exp+transpose of x (blocks x<64), plus weight-exp (written directly in MFMA
// fragment order) and exT guard-row zeroing (blocks x>=64, y==0).
// ewb fragment layout: idx = (((t*8+og)*4+cc)*64 + li)*8 + e holds
// exp(W[og*16+(li&15)][cc*32+(li>>4)*8+e]) at tap t -- so tropconv loads a
// whole A-fragment as one coalesced 1KB wave read straight into VGPRs.
__global__ __launch_bounds__(256) void exp_x_kernel(
        const float* __restrict__ x, __hip_bfloat16* __restrict__ exT,
        const float* __restrict__ w, __hip_bfloat16* __restrict__ ewb) {
    if (blockIdx.x >= 64) {
        if (blockIdx.y != 0) return;
        int base = (blockIdx.x - 64) * 256 + threadIdx.x;   // 18 blocks * 256 = 4608
        #pragma unroll
        for (int i = 0; i < 32; ++i) {
            int idx = base + 4608 * i;                      // covers 147456 = NWELEM+NGUARD
            if (idx < NWELEM) {
                int e  = idx & 7;
                int li = (idx >> 3) & 63;
                int cc = (idx >> 9) & 3;
                int blk = idx >> 11;                        // 0..55
                int og = blk & 7, t = blk >> 3;
                int o  = og * 16 + (li & 15);
                int ch = cc * 32 + ((li >> 4) << 3) + e;
                ewb[idx] = __float2bfloat16(__expf(w[(o * CIN_ + ch) * KW_ + t]));
            } else {
                int j  = idx - NWELEM;
                int b  = j >> 10, rr = (j >> 7) & 7, c = j & 127;
                int r  = (rr < 3) ? rr : (4096 + rr);       // rows 0,1,2 and 4099..4103
                exT[((size_t)b * RPB + r) * CIN_ + c] = __float2bfloat16(0.0f);
            }
        }
        return;
    }

    __shared__ __align__(16) __hip_bfloat16 tileT[64 * 136];   // 17408 B
    const int b  = blockIdx.y;
    const int l0 = blockIdx.x * 64;
    const int tid = threadIdx.x;
    const float* xb = x + (size_t)b * CIN_ * L_ + l0;

    #pragma unroll
    for (int i = 0; i < 8; ++i) {
        int idx = tid + 256 * i;
        int c   = idx >> 4;               // 0..127
        int lv4 = (idx & 15) * 4;         // l offset 0..60
        f32x4 v = *(const f32x4*)(xb + (size_t)c * L_ + lv4);
        #pragma unroll
        for (int k2 = 0; k2 < 4; ++k2) {
            int l  = lv4 + k2;
            int sw = (l >> 2) & 15;
            tileT[l * 136 + (c ^ (sw << 3))] = __float2bfloat16(__expf(v[k2]));
        }
    }
    __syncthreads();

    __hip_bfloat16* dst = exT + ((size_t)b * RPB + l0 + PAD_) * CIN_;
    #pragma unroll
    for (int i = 0; i < 4; ++i) {
        int idx = tid + 256 * i;
        int l  = idx >> 4;                // 16 lanes per row -> 256 B coalesced
        int gc = idx & 15;                // channel granule (8 ch)
        int sw = (l >> 2) & 15;
        bf16x8 vv = *(const bf16x8*)&tileT[l * 136 + ((gc ^ sw) << 3)];
        *(bf16x8*)(dst + (size_t)l * CIN_ + gc * 8) = vv;
    }
}

// Conv GEMM, Round 7 = Round-5 structure (the verified best: A global->VGPR
// from fragment-ordered ewb, B-only LDS at 0.25 KB-reads/MFMA, one barrier
// per block) at DOUBLED occupancy. R6's in-kernel fusion regressed (spill +
// ds_write_b16 scatter); reverted. R5 ran 8 waves/CU (2/SIMD) -- too little
// TLP to hide A-load latency + LDS bursts (MfmaUtil pinned ~25% across all
// 2-waves/SIMD variants). NW_=128 shrinks sX to 34.8 KB -> 4 de-phased
// blocks/CU (16 waves, 4/SIMD). Wave tile 64o x 64w: acc 4x4 (64 VGPR),
// B 4 LDS-reads + A 4 global-reads per 16 MFMAs. __launch_bounds__(256,4)
// pins the 128-VGPR budget 4/SIMD needs.
__global__ __launch_bounds__(256, 4) void tropconv_kernel(
        const __hip_bfloat16* __restrict__ exT,
        const __hip_bfloat16* __restrict__ ewb,
        const float* __restrict__ bias,
        float* __restrict__ out) {
    __shared__ __align__(16) __hip_bfloat16 sX[SX_ELEMS];   // 34816 B

    const int tid  = threadIdx.x;
    const int lane = tid & 63;
    const int wave = tid >> 6;
    const int wm   = wave >> 1;            // 0..1: o half (64 each)
    const int wn   = wave & 1;             // 0..1: w half (64 each)
    const int l15  = lane & 15;
    const int q    = lane >> 4;

    const int b  = blockIdx.y;
    const int w0 = blockIdx.x * NW_;
    const __hip_bfloat16* exb = exT + ((size_t)b * RPB + w0) * CIN_;

    // ---- stage X once: 136 rows x 16 granules = 2176 granules.
    // LDS slot j of row p holds channel-granule j^(p&7) (read applies same XOR).
    #pragma unroll
    for (int s = 0; s < 8; ++s) {
        int gx = tid + 256 * s;
        int p = gx >> 4, j = gx & 15;
        gl2lds16(exb + (p << 7) + ((j ^ (p & 7)) << 3), &sX[gx * 8]);
    }
    if (tid < 128) {                       // rows 128..135; waves 0,1 fully active
        int gx = tid + 2048;
        int p = gx >> 4, j = gx & 15;
        gl2lds16(exb + (p << 7) + ((j ^ (p & 7)) << 3), &sX[gx * 8]);
    }

    f32x4 acc[4][4];
    #pragma unroll
    for (int i = 0; i < 4; ++i)
        #pragma unroll
        for (int j = 0; j < 4; ++j)
            acc[i][j] = (f32x4){0.f, 0.f, 0.f, 0.f};

    __syncthreads();                       // the block's ONE barrier

    // A-frag (t,cc,mi): 1KB coalesced global load, lane li holds
    // W[og*16+(li&15)][cc*32+(li>>4)*8..+8], og = wm*4+mi.
#define ALOAD(AF, T, CC)                                                     \
    do {                                                                     \
        _Pragma("unroll")                                                    \
        for (int mi = 0; mi < 4; ++mi)                                       \
            AF[mi] = *(const bf16x8*)&ewb[(((((T) * 8 + wm * 4 + mi) * 4     \
                                             + (CC)) << 6) + lane) * 8];     \
    } while (0)

    // B-reads + 16 MFMAs for one (tap, chunk); b128 per lane, <=2-way banks.
#define BDOT(AF, T, CC)                                                      \
    do {                                                                     \
        bf16x8 bx[4];                                                        \
        _Pragma("unroll")                                                    \
        for (int ni = 0; ni < 4; ++ni) {                                     \
            int p = wn * 64 + ni * 16 + l15 + (T);                           \
            int g = ((CC) * 4 + q) ^ (p & 7);                                \
            bx[ni] = *(const bf16x8*)&sX[(p << 7) + (g << 3)];               \
        }                                                                    \
        __builtin_amdgcn_s_setprio(1);                                       \
        _Pragma("unroll")                                                    \
        for (int mi = 0; mi < 4; ++mi)                                       \
            _Pragma("unroll")                                                \
            for (int ni = 0; ni < 4; ++ni)                                   \
                acc[mi][ni] = __builtin_amdgcn_mfma_f32_16x16x32_bf16(       \
                    AF[mi], bx[ni], acc[mi][ni], 0, 0, 0);                   \
        __builtin_amdgcn_s_setprio(0);                                       \
    } while (0)

    {
        bf16x8 afA[4], afB[4];
        ALOAD(afA, 0, 0);
        ALOAD(afB, 1, 0);  BDOT(afA, 0, 0);
        ALOAD(afA, 2, 0);  BDOT(afB, 1, 0);
        ALOAD(afB, 3, 0);  BDOT(afA, 2, 0);
        ALOAD(afA, 4, 0);  BDOT(afB, 3, 0);
        ALOAD(afB, 5, 0);  BDOT(afA, 4, 0);
        ALOAD(afA, 6, 0);  BDOT(afB, 5, 0);
        ALOAD(afB, 0, 1);  BDOT(afA, 6, 0);
        ALOAD(afA, 1, 1);  BDOT(afB, 0, 1);
        ALOAD(afB, 2, 1);  BDOT(afA, 1, 1);
        ALOAD(afA, 3, 1);  BDOT(afB, 2, 1);
        ALOAD(afB, 4, 1);  BDOT(afA, 3, 1);
        ALOAD(afA, 5, 1);  BDOT(afB, 4, 1);
        ALOAD(afB, 6, 1);  BDOT(afA, 5, 1);
        ALOAD(afA, 0, 2);  BDOT(afB, 6, 1);
        ALOAD(afB, 1, 2);  BDOT(afA, 0, 2);
        ALOAD(afA, 2, 2);  BDOT(afB, 1, 2);
        ALOAD(afB, 3, 2);  BDOT(afA, 2, 2);
        ALOAD(afA, 4, 2);  BDOT(afB, 3, 2);
        ALOAD(afB, 5, 2);  BDOT(afA, 4, 2);
        ALOAD(afA, 6, 2);  BDOT(afB, 5, 2);
        ALOAD(afB, 0, 3);  BDOT(afA, 6, 2);
        ALOAD(afA, 1, 3);  BDOT(afB, 0, 3);
        ALOAD(afB, 2, 3);  BDOT(afA, 1, 3);
        ALOAD(afA, 3, 3);  BDOT(afB, 2, 3);
        ALOAD(afB, 4, 3);  BDOT(afA, 3, 3);
        ALOAD(afA, 5, 3);  BDOT(afB, 4, 3);
        ALOAD(afB, 6, 3);  BDOT(afA, 5, 3);
                           BDOT(afB, 6, 3);
    }
#undef ALOAD
#undef BDOT

    // epilogue: y = log(s) + bias[o]; C/D: col=lane&15 (w), row=q*4+reg (cout)
    float* outb = out + (size_t)b * COUT_ * L_;
    #pragma unroll
    for (int mi = 0; mi < 4; ++mi) {
        #pragma unroll
        for (int r = 0; r < 4; ++r) {
            int o = wm * 64 + mi * 16 + q * 4 + r;
            float bv = bias[o];
            #pragma unroll
            for (int ni = 0; ni < 4; ++ni) {
                int w = w0 + wn * 64 + ni * 16 + l15;
                outb[(size_t)o * L_ + w] = __logf(acc[mi][ni][r]) + bv;
            }
        }
    }
}

extern "C" void kernel_launch(void* const* d_in, const int* in_sizes, int n_in,
                              void* d_out, int out_size, void* d_ws, size_t ws_size,
                              hipStream_t stream) {
    const float* x    = (const float*)d_in[0];   // (32,128,4096) f32
    const float* wgt  = (const float*)d_in[1];   // (128,128,7)   f32
    const float* bias = (const float*)d_in[2];   // (128,)        f32
    float* out = (float*)d_out;                  // (32,128,4096) f32

    // workspace: exT (32 x 4104 x 128 bf16 = 33,619,968 B), then ewb (229 KB)
    __hip_bfloat16* exT = (__hip_bfloat16*)d_ws;
    __hip_bfloat16* ewb = (__hip_bfloat16*)((char*)d_ws + (size_t)B_N * RPB * CIN_ * 2);

    exp_x_kernel<<<dim3(64 + 18, B_N), 256, 0, stream>>>(x, exT, wgt, ewb);
    tropconv_kernel<<<dim3(L_ / NW_, B_N), 256, 0, stream>>>(exT, ewb, bias, out);
}

// Round 8
// 147.733 us; speedup vs baseline: 1.1910x; 1.1623x over previous
//
#include <hip/hip_runtime.h>
#include <hip/hip_bf16.h>
#include <cstdint>
#include <cstddef>

#define B_N   32
#define CIN_  128
#define COUT_ 128
#define KW_   7
#define L_    4096
#define PAD_  3
#define NW_   128      // w-positions per block tile
#define RPB   4104     // exT rows per batch: r = l + 3, guards r<3 and r>4098
#define NWELEM (KW_ * COUT_ * CIN_)   // 114688
#define NGUARD (B_N * 8 * CIN_)       // 32768

#define SX_ROWS  136                  // 134 used (128 w + 6 taps); pad to 136
#define SX_ELEMS (SX_ROWS * CIN_)     // 17408 bf16 = 34816 B -> 3 blocks/CU

typedef __attribute__((ext_vector_type(8))) short  bf16x8;
typedef __attribute__((ext_vector_type(4))) float  f32x4;

__device__ __forceinline__ void gl2lds16(const void* g, void* l) {
    __builtin_amdgcn_global_load_lds(
        (const __attribute__((address_space(1))) unsigned int*)g,
        (__attribute__((address_space(3))) unsigned int*)l, 16, 0, 0);
}

// exp+transpose of x (blocks x<64), plus weight-exp (written directly in MFMA
// fragment order) and exT guard-row zeroing (blocks x>=64, y==0).
// ewb fragment layout: idx = (((t*8+og)*4+cc)*64 + li)*8 + e holds
// exp(W[og*16+(li&15)][cc*32+(li>>4)*8+e]) at tap t -- so tropconv loads a
// whole A-fragment as one coalesced 1KB wave read straight into VGPRs.
__global__ __launch_bounds__(256) void exp_x_kernel(
        const float* __restrict__ x, __hip_bfloat16* __restrict__ exT,
        const float* __restrict__ w, __hip_bfloat16* __restrict__ ewb) {
    if (blockIdx.x >= 64) {
        if (blockIdx.y != 0) return;
        int base = (blockIdx.x - 64) * 256 + threadIdx.x;   // 18 blocks * 256 = 4608
        #pragma unroll
        for (int i = 0; i < 32; ++i) {
            int idx = base + 4608 * i;                      // covers 147456 = NWELEM+NGUARD
            if (idx < NWELEM) {
                int e  = idx & 7;
                int li = (idx >> 3) & 63;
                int cc = (idx >> 9) & 3;
                int blk = idx >> 11;                        // 0..55
                int og = blk & 7, t = blk >> 3;
                int o  = og * 16 + (li & 15);
                int ch = cc * 32 + ((li >> 4) << 3) + e;
                ewb[idx] = __float2bfloat16(__expf(w[(o * CIN_ + ch) * KW_ + t]));
            } else {
                int j  = idx - NWELEM;
                int b  = j >> 10, rr = (j >> 7) & 7, c = j & 127;
                int r  = (rr < 3) ? rr : (4096 + rr);       // rows 0,1,2 and 4099..4103
                exT[((size_t)b * RPB + r) * CIN_ + c] = __float2bfloat16(0.0f);
            }
        }
        return;
    }

    __shared__ __align__(16) __hip_bfloat16 tileT[64 * 136];   // 17408 B
    const int b  = blockIdx.y;
    const int l0 = blockIdx.x * 64;
    const int tid = threadIdx.x;
    const float* xb = x + (size_t)b * CIN_ * L_ + l0;

    #pragma unroll
    for (int i = 0; i < 8; ++i) {
        int idx = tid + 256 * i;
        int c   = idx >> 4;               // 0..127
        int lv4 = (idx & 15) * 4;         // l offset 0..60
        f32x4 v = *(const f32x4*)(xb + (size_t)c * L_ + lv4);
        #pragma unroll
        for (int k2 = 0; k2 < 4; ++k2) {
            int l  = lv4 + k2;
            int sw = (l >> 2) & 15;
            tileT[l * 136 + (c ^ (sw << 3))] = __float2bfloat16(__expf(v[k2]));
        }
    }
    __syncthreads();

    __hip_bfloat16* dst = exT + ((size_t)b * RPB + l0 + PAD_) * CIN_;
    #pragma unroll
    for (int i = 0; i < 4; ++i) {
        int idx = tid + 256 * i;
        int l  = idx >> 4;                // 16 lanes per row -> 256 B coalesced
        int gc = idx & 15;                // channel granule (8 ch)
        int sw = (l >> 2) & 15;
        bf16x8 vv = *(const bf16x8*)&tileT[l * 136 + ((gc ^ sw) << 3)];
        *(bf16x8*)(dst + (size_t)l * CIN_ + gc * 8) = vv;
    }
}

// Conv GEMM, Round 8 = Round-7 geometry at a NON-SPILLING register budget.
// R7 post-mortem: __launch_bounds__(256,4) -> 128 unified regs/wave; acc
// alone is 64, working set squeezed into 64 VGPRs -> scratch spill (FETCH
// +31MB, WRITE +52MB, MfmaUtil 20%). One-variable fix: min-waves 3 -> 170
// regs/wave (64 acc + ~100 VGPR, no spill), 3 blocks/CU (12 waves, 3/SIMD,
// 1.5x R5's TLP). Grid = 1024 blocks = 4 work-units per CU with 3 resident:
// block generations stagger, so stage/epilogue of one block overlaps MFMA
// of others (R5's exactly-resident grid had zero such slack).
// Structure otherwise R5's verified best: A global->VGPR from fragment-
// ordered ewb (L2-resident), B-only LDS 0.25 KB-reads/MFMA, one barrier.
__global__ __launch_bounds__(256, 3) void tropconv_kernel(
        const __hip_bfloat16* __restrict__ exT,
        const __hip_bfloat16* __restrict__ ewb,
        const float* __restrict__ bias,
        float* __restrict__ out) {
    __shared__ __align__(16) __hip_bfloat16 sX[SX_ELEMS];   // 34816 B

    const int tid  = threadIdx.x;
    const int lane = tid & 63;
    const int wave = tid >> 6;
    const int wm   = wave >> 1;            // 0..1: o half (64 each)
    const int wn   = wave & 1;             // 0..1: w half (64 each)
    const int l15  = lane & 15;
    const int q    = lane >> 4;

    const int b  = blockIdx.y;
    const int w0 = blockIdx.x * NW_;
    const __hip_bfloat16* exb = exT + ((size_t)b * RPB + w0) * CIN_;

    // ---- stage X once: 136 rows x 16 granules = 2176 granules.
    // LDS slot j of row p holds channel-granule j^(p&7) (read applies same XOR).
    #pragma unroll
    for (int s = 0; s < 8; ++s) {
        int gx = tid + 256 * s;
        int p = gx >> 4, j = gx & 15;
        gl2lds16(exb + (p << 7) + ((j ^ (p & 7)) << 3), &sX[gx * 8]);
    }
    if (tid < 128) {                       // rows 128..135; waves 0,1 fully active
        int gx = tid + 2048;
        int p = gx >> 4, j = gx & 15;
        gl2lds16(exb + (p << 7) + ((j ^ (p & 7)) << 3), &sX[gx * 8]);
    }

    f32x4 acc[4][4];
    #pragma unroll
    for (int i = 0; i < 4; ++i)
        #pragma unroll
        for (int j = 0; j < 4; ++j)
            acc[i][j] = (f32x4){0.f, 0.f, 0.f, 0.f};

    __syncthreads();                       // the block's ONE barrier

    // A-frag (t,cc,mi): 1KB coalesced global load, lane li holds
    // W[og*16+(li&15)][cc*32+(li>>4)*8..+8], og = wm*4+mi.
#define ALOAD(AF, T, CC)                                                     \
    do {                                                                     \
        _Pragma("unroll")                                                    \
        for (int mi = 0; mi < 4; ++mi)                                       \
            AF[mi] = *(const bf16x8*)&ewb[(((((T) * 8 + wm * 4 + mi) * 4     \
                                             + (CC)) << 6) + lane) * 8];     \
    } while (0)

    // B-reads + 16 MFMAs for one (tap, chunk); b128 per lane, <=2-way banks.
#define BDOT(AF, T, CC)                                                      \
    do {                                                                     \
        bf16x8 bx[4];                                                        \
        _Pragma("unroll")                                                    \
        for (int ni = 0; ni < 4; ++ni) {                                     \
            int p = wn * 64 + ni * 16 + l15 + (T);                           \
            int g = ((CC) * 4 + q) ^ (p & 7);                                \
            bx[ni] = *(const bf16x8*)&sX[(p << 7) + (g << 3)];               \
        }                                                                    \
        __builtin_amdgcn_s_setprio(1);                                       \
        _Pragma("unroll")                                                    \
        for (int mi = 0; mi < 4; ++mi)                                       \
            _Pragma("unroll")                                                \
            for (int ni = 0; ni < 4; ++ni)                                   \
                acc[mi][ni] = __builtin_amdgcn_mfma_f32_16x16x32_bf16(       \
                    AF[mi], bx[ni], acc[mi][ni], 0, 0, 0);                   \
        __builtin_amdgcn_s_setprio(0);                                       \
    } while (0)

    {
        bf16x8 afA[4], afB[4];
        ALOAD(afA, 0, 0);
        ALOAD(afB, 1, 0);  BDOT(afA, 0, 0);
        ALOAD(afA, 2, 0);  BDOT(afB, 1, 0);
        ALOAD(afB, 3, 0);  BDOT(afA, 2, 0);
        ALOAD(afA, 4, 0);  BDOT(afB, 3, 0);
        ALOAD(afB, 5, 0);  BDOT(afA, 4, 0);
        ALOAD(afA, 6, 0);  BDOT(afB, 5, 0);
        ALOAD(afB, 0, 1);  BDOT(afA, 6, 0);
        ALOAD(afA, 1, 1);  BDOT(afB, 0, 1);
        ALOAD(afB, 2, 1);  BDOT(afA, 1, 1);
        ALOAD(afA, 3, 1);  BDOT(afB, 2, 1);
        ALOAD(afB, 4, 1);  BDOT(afA, 3, 1);
        ALOAD(afA, 5, 1);  BDOT(afB, 4, 1);
        ALOAD(afB, 6, 1);  BDOT(afA, 5, 1);
        ALOAD(afA, 0, 2);  BDOT(afB, 6, 1);
        ALOAD(afB, 1, 2);  BDOT(afA, 0, 2);
        ALOAD(afA, 2, 2);  BDOT(afB, 1, 2);
        ALOAD(afB, 3, 2);  BDOT(afA, 2, 2);
        ALOAD(afA, 4, 2);  BDOT(afB, 3, 2);
        ALOAD(afB, 5, 2);  BDOT(afA, 4, 2);
        ALOAD(afA, 6, 2);  BDOT(afB, 5, 2);
        ALOAD(afB, 0, 3);  BDOT(afA, 6, 2);
        ALOAD(afA, 1, 3);  BDOT(afB, 0, 3);
        ALOAD(afB, 2, 3);  BDOT(afA, 1, 3);
        ALOAD(afA, 3, 3);  BDOT(afB, 2, 3);
        ALOAD(afB, 4, 3);  BDOT(afA, 3, 3);
        ALOAD(afA, 5, 3);  BDOT(afB, 4, 3);
        ALOAD(afB, 6, 3);  BDOT(afA, 5, 3);
                           BDOT(afB, 6, 3);
    }
#undef ALOAD
#undef BDOT

    // epilogue: y = log(s) + bias[o]; C/D: col=lane&15 (w), row=q*4+reg (cout)
    float* outb = out + (size_t)b * COUT_ * L_;
    #pragma unroll
    for (int mi = 0; mi < 4; ++mi) {
        #pragma unroll
        for (int r = 0; r < 4; ++r) {
            int o = wm * 64 + mi * 16 + q * 4 + r;
            float bv = bias[o];
            #pragma unroll
            for (int ni = 0; ni < 4; ++ni) {
                int w = w0 + wn * 64 + ni * 16 + l15;
                outb[(size_t)o * L_ + w] = __logf(acc[mi][ni][r]) + bv;
            }
        }
    }
}

extern "C" void kernel_launch(void* const* d_in, const int* in_sizes, int n_in,
                              void* d_out, int out_size, void* d_ws, size_t ws_size,
                              hipStream_t stream) {
    const float* x    = (const float*)d_in[0];   // (32,128,4096) f32
    const float* wgt  = (const float*)d_in[1];   // (128,128,7)   f32
    const float* bias = (const float*)d_in[2];   // (128,)        f32
    float* out = (float*)d_out;                  // (32,128,4096) f32

    // workspace: exT (32 x 4104 x 128 bf16 = 33,619,968 B), then ewb (229 KB)
    __hip_bfloat16* exT = (__hip_bfloat16*)d_ws;
    __hip_bfloat16* ewb = (__hip_bfloat16*)((char*)d_ws + (size_t)B_N * RPB * CIN_ * 2);

    exp_x_kernel<<<dim3(64 + 18, B_N), 256, 0, stream>>>(x, exT, wgt, ewb);
    tropconv_kernel<<<dim3(L_ / NW_, B_N), 256, 0, stream>>>(exT, ewb, bias, out);
}